// Round 4
// baseline (1019.355 us; speedup 1.0000x reference)
//
#include <hip/hip_runtime.h>

#define NN 8192
#define EE 524288
#define HPAD 256   // hidden 200 padded to 256
#define NP 640     // 3*200 output cols padded to 640 (5 x 128 tiles)

using s16x8 = __attribute__((ext_vector_type(8))) short;
using f32x4 = __attribute__((ext_vector_type(4))) float;

__device__ __forceinline__ unsigned short f2b(float f) {
    unsigned u = __float_as_uint(f);
    u = (u + 0x7FFFu + ((u >> 16) & 1u)) >> 16;   // round-to-nearest-even
    return (unsigned short)u;
}
__device__ __forceinline__ float b2f(unsigned short u) {
    return __uint_as_float((unsigned)u << 16);
}

// async 16B global->LDS (direct DMA). Dest is wave-uniform base + lane*16.
__device__ __forceinline__ void async16(const unsigned short* g, unsigned short* l)
{
    __builtin_amdgcn_global_load_lds(
        (const __attribute__((address_space(1))) unsigned int*)g,
        (__attribute__((address_space(3))) unsigned int*)l, 16, 0, 0);
}

// ---------------- conversions ----------------

__global__ void cvt_f2b_kernel(const float* __restrict__ in,
                               unsigned short* __restrict__ out, int n4)
{
    int i = blockIdx.x * 256 + threadIdx.x;
    if (i >= n4) return;
    float4 v = ((const float4*)in)[i];
    ushort4 o;
    o.x = f2b(v.x); o.y = f2b(v.y); o.z = f2b(v.z); o.w = f2b(v.w);
    ((ushort4*)out)[i] = o;
}

// h [8192,200] f32 -> hb [8192,HPAD] bf16, zero-padded cols 200..255
__global__ void cvt_h_kernel(const float* __restrict__ h,
                             unsigned short* __restrict__ hb)
{
    int i = blockIdx.x * 256 + threadIdx.x;      // i in [0, 8192*64)
    int n = i >> 6, j4 = (i & 63) << 2;
    ushort4 o = {0, 0, 0, 0};
    if (j4 < 200) {
        const float* p = h + (size_t)n * 200 + j4;
        o.x = f2b(p[0]); o.y = f2b(p[1]); o.z = f2b(p[2]); o.w = f2b(p[3]);
    }
    ((ushort4*)hb)[i] = o;
}

// out[n][k] (bf16, [Nout, Kout]) = concat(w0|w1|w2)[k][n], zero-padded.
__global__ void transpose_w_kernel(const float* __restrict__ w0,
                                   const float* __restrict__ w1,
                                   const float* __restrict__ w2,
                                   unsigned short* __restrict__ out,
                                   int Kout, int Kreal, int Nreal)
{
    __shared__ float tile[32][33];
    const int kb = blockIdx.x << 5;
    const int nb = blockIdx.y << 5;
    const int tx = threadIdx.x, ty = threadIdx.y;   // 32 x 8
    const int n = nb + tx;
    const float* w = (n < 200) ? w0 : (n < 400) ? w1 : w2;
    const int c = (n < 200) ? n : (n < 400) ? n - 200 : n - 400;
#pragma unroll
    for (int i = 0; i < 4; ++i) {
        const int k = kb + ty + (i << 3);
        float v = 0.f;
        if (n < Nreal && k < Kreal) v = w[(size_t)k * 200 + c];
        tile[ty + (i << 3)][tx] = v;
    }
    __syncthreads();
#pragma unroll
    for (int i = 0; i < 4; ++i) {
        const int nn = nb + ty + (i << 3);
        out[(size_t)nn * Kout + kb + tx] = f2b(tile[tx][ty + (i << 3)]);
    }
}

// ---------------- MFMA GEMM with global_load_lds staging ----------------
// C_plane[z][8192, ldc] = A[:, z*KC:(z+1)*KC] @ BT[:, z*KC:(z+1)*KC]^T
// LDS layout: slot s of row r holds k-chunk s^(r&7)  (conflict-free ds_read).
// Staging: lane l=(r=l>>3, c=l&7) DMAs global chunk c^r of row (w*8+r), which
// lands at wave-uniform-base + l*16 = slot c of row r  => invariant holds.
__global__ __launch_bounds__(256) void gemm_mfma(
    const unsigned short* __restrict__ A,
    const unsigned short* __restrict__ BT,
    float* __restrict__ C, int lda, int KC, int ldc, size_t planeStride)
{
    __shared__ unsigned short As[128 * 64];
    __shared__ unsigned short Bs[128 * 64];
    const int tid  = threadIdx.x;
    const int lane = tid & 63;
    const int w    = tid >> 6;
    const int row0 = blockIdx.y << 7;
    const int col0 = blockIdx.x << 7;
    const int z    = blockIdx.z;
    const int wm = (w >> 1) << 6;
    const int wn = (w & 1) << 6;

    const int sr = lane >> 3;             // row within wave's 8-row strip
    const int sc = (lane & 7) ^ sr;       // global chunk to fetch (xor-permuted)
    const size_t kbase = (size_t)z * KC + ((size_t)sc << 3);
    const unsigned short* aG = A  + (size_t)(row0 + w * 8 + sr) * lda + kbase;
    const unsigned short* bG = BT + (size_t)(col0 + w * 8 + sr) * lda + kbase;

    const f32x4 zero = {0.f, 0.f, 0.f, 0.f};
    f32x4 acc[4][4];
#pragma unroll
    for (int i = 0; i < 4; ++i)
#pragma unroll
        for (int j = 0; j < 4; ++j) acc[i][j] = zero;

    for (int k0 = 0; k0 < KC; k0 += 64) {
        __syncthreads();                     // prev compute done with LDS
#pragma unroll
        for (int it = 0; it < 4; ++it) {
            async16(aG + (size_t)(it * 32) * lda + k0,
                    As + ((it * 32 + w * 8) << 6));
            async16(bG + (size_t)(it * 32) * lda + k0,
                    Bs + ((it * 32 + w * 8) << 6));
        }
        __syncthreads();                     // drains vmcnt, tile ready
#pragma unroll
        for (int kk = 0; kk < 2; ++kk) {
            const int q  = (kk << 2) + (lane >> 4);
            const int sl = (q ^ (lane & 7)) << 3;
            s16x8 af[4], bfv[4];
#pragma unroll
            for (int i = 0; i < 4; ++i) {
                const int rm = wm + (i << 4) + (lane & 15);
                af[i]  = *(const s16x8*)(As + (rm << 6) + sl);
                const int rn = wn + (i << 4) + (lane & 15);
                bfv[i] = *(const s16x8*)(Bs + (rn << 6) + sl);
            }
#pragma unroll
            for (int i = 0; i < 4; ++i)
#pragma unroll
                for (int j = 0; j < 4; ++j)
                    acc[i][j] = __builtin_amdgcn_mfma_f32_16x16x32_bf16(
                        af[i], bfv[j], acc[i][j], 0, 0, 0);
        }
    }

    float* Cp = C + (size_t)z * planeStride;
    const int cr = (lane >> 4) << 2;      // C/D: row = quad*4 + r, col = lane&15
    const int cc = lane & 15;
#pragma unroll
    for (int i = 0; i < 4; ++i)
#pragma unroll
        for (int j = 0; j < 4; ++j)
#pragma unroll
            for (int r = 0; r < 4; ++r)
                Cp[(size_t)(row0 + wm + (i << 4) + cr + r) * ldc
                   + (col0 + wn + (j << 4) + cc)] = acc[i][j][r];
}

// ---------------- combine: fp32 self + two contiguous bf16 message arrays ----
// y_simb / y_ratb: [8192,200] bf16 (3.28 MB each -> fits per-XCD 4MB L2)
__global__ void combine_kernel(const float* __restrict__ p0,
                               const float* __restrict__ p1,
                               float* __restrict__ y_self,
                               unsigned short* __restrict__ y_simb,
                               unsigned short* __restrict__ y_ratb)
{
    int t = blockIdx.x * 256 + threadIdx.x;    // n*50 + j4chunk
    int n = t / 50, j4 = (t - n * 50) << 2;
    const float* a = p0 + (size_t)n * NP;
    float4 s = *(const float4*)(a + j4);
    float4 m = *(const float4*)(a + 200 + j4);
    float4 r = *(const float4*)(a + 400 + j4);
    if (p1) {
        const float* b = p1 + (size_t)n * NP;
        float4 s2 = *(const float4*)(b + j4);
        float4 m2 = *(const float4*)(b + 200 + j4);
        float4 r2 = *(const float4*)(b + 400 + j4);
        s.x += s2.x; s.y += s2.y; s.z += s2.z; s.w += s2.w;
        m.x += m2.x; m.y += m2.y; m.z += m2.z; m.w += m2.w;
        r.x += r2.x; r.y += r2.y; r.z += r2.z; r.w += r2.w;
    }
    *(float4*)(y_self + (size_t)n * 200 + j4) = s;
    ushort4 mo, ro;
    mo.x = f2b(m.x); mo.y = f2b(m.y); mo.z = f2b(m.z); mo.w = f2b(m.w);
    ro.x = f2b(r.x); ro.y = f2b(r.y); ro.z = f2b(r.z); ro.w = f2b(r.w);
    *(ushort4*)(y_simb + (size_t)n * 200 + j4) = mo;
    *(ushort4*)(y_ratb + (size_t)n * 200 + j4) = ro;
}

// ---------------- edge sort (counting sort by dst, payload = (src, eid)) -----

__global__ void hist_kernel(const int* __restrict__ edges, int* __restrict__ deg)
{
    int e = blockIdx.x * 256 + threadIdx.x;
    if (e < EE) atomicAdd(&deg[edges[EE + e]], 1);
}

__global__ void scan_kernel(const int* __restrict__ deg,
                            int* __restrict__ off, int* __restrict__ pos)
{
    __shared__ int part[256];
    const int t = threadIdx.x;
    const int base = t * 32;
    int s = 0;
#pragma unroll
    for (int i = 0; i < 32; ++i) s += deg[base + i];
    part[t] = s;
    __syncthreads();
    for (int d = 1; d < 256; d <<= 1) {
        int v = (t >= d) ? part[t - d] : 0;
        __syncthreads();
        part[t] += v;
        __syncthreads();
    }
    int run = (t == 0) ? 0 : part[t - 1];
    for (int i = 0; i < 32; ++i) {
        off[base + i] = run;
        pos[base + i] = run;
        run += deg[base + i];
    }
    if (t == 255) off[NN] = run;
}

__global__ void reorder_kernel(const int* __restrict__ edges,
                               int* __restrict__ pos, int2* __restrict__ se)
{
    int e = blockIdx.x * 256 + threadIdx.x;
    if (e >= EE) return;
    int p = atomicAdd(&pos[edges[EE + e]], 1);
    se[p] = make_int2(edges[e], e);
}

// ---------------- aggregation pass (one message type per launch) ----------
// pass A (y_self != null): h = y_self + bias + sum_msg
// pass B (y_self == null): h = (relu?)(h + sum_msg)
__global__ __launch_bounds__(256) void agg_pass_kernel(
    const unsigned short* __restrict__ msg,   // [8192,200] bf16, L2-resident
    const int* __restrict__ off, const int2* __restrict__ se,
    const float* __restrict__ y_self, const float* __restrict__ bias,
    float* __restrict__ h, int relu)
{
    __shared__ float part[4][200];
    const int n = blockIdx.x;
    const int w = threadIdx.x >> 6;
    const int lane = threadIdx.x & 63;
    const int j4 = lane << 2;
    const bool act = lane < 50;

    float4 acc = {0.f, 0.f, 0.f, 0.f};
    const int e1 = off[n + 1];
    for (int i = off[n] + w; i < e1; i += 4) {
        const int src = se[i].x;
        if (act) {
            ushort4 v = *(const ushort4*)(msg + (size_t)src * 200 + j4);
            acc.x += b2f(v.x); acc.y += b2f(v.y);
            acc.z += b2f(v.z); acc.w += b2f(v.w);
        }
    }
    if (act) *(float4*)&part[w][j4] = acc;
    __syncthreads();
    const int j = threadIdx.x;
    if (j < 200) {
        float v = part[0][j] + part[1][j] + part[2][j] + part[3][j];
        if (y_self) v += y_self[(size_t)n * 200 + j] + bias[j];
        else        v += h[(size_t)n * 200 + j];
        if (relu) v = fmaxf(v, 0.f);
        h[(size_t)n * 200 + j] = v;
    }
}

// ---------------- decoder: dst-grouped, hQ gathered from L2-resident array ---
__global__ __launch_bounds__(256) void pred_kernel(
    const unsigned short* __restrict__ hQb,  // [8192, HPAD] bf16
    const unsigned short* __restrict__ h2b,  // [8192, HPAD] bf16
    const int* __restrict__ off, const int2* __restrict__ se,
    const int* __restrict__ mask, float* __restrict__ out)
{
    const int n = blockIdx.x;
    const int w = threadIdx.x >> 6;
    const int lane = threadIdx.x & 63;
    float4 b = {0.f, 0.f, 0.f, 0.f};
    if (lane < 50) {
        ushort4 v = *(const ushort4*)(h2b + ((size_t)n << 8) + (lane << 2));
        b.x = b2f(v.x); b.y = b2f(v.y); b.z = b2f(v.z); b.w = b2f(v.w);
    }
    const int e1 = off[n + 1];
    for (int i = off[n] + w; i < e1; i += 4) {
        const int2 p = ((const int2*)se)[i];
        float s = 0.f;
        if (lane < 50) {
            ushort4 a = *(const ushort4*)(hQb + ((size_t)p.x << 8) + (lane << 2));
            s = fmaf(b2f(a.x), b.x, fmaf(b2f(a.y), b.y,
                fmaf(b2f(a.z), b.z, b2f(a.w) * b.w)));
        }
#pragma unroll
        for (int o = 32; o > 0; o >>= 1) s += __shfl_down(s, o, 64);
        if (lane == 0) out[p.y] = mask[p.y] ? (s + 3.5f) : 0.f;
    }
}

// ---------------- launch ----------------
extern "C" void kernel_launch(void* const* d_in, const int* in_sizes, int n_in,
                              void* d_out, int out_size, void* d_ws, size_t ws_size,
                              hipStream_t stream)
{
    const float* x       = (const float*)d_in[0];
    const int*   e_sim   = (const int*)d_in[1];
    const int*   e_rat   = (const int*)d_in[2];
    const int*   mask    = (const int*)d_in[3];
    const float* w1_self = (const float*)d_in[4];
    const float* w1_sim  = (const float*)d_in[5];
    const float* w1_rat  = (const float*)d_in[6];
    const float* b1      = (const float*)d_in[7];
    const float* w2_self = (const float*)d_in[8];
    const float* w2_sim  = (const float*)d_in[9];
    const float* w2_rat  = (const float*)d_in[10];
    const float* b2      = (const float*)d_in[11];
    const float* Q       = (const float*)d_in[12];
    float* out = (float*)d_out;

    char* p = (char*)d_ws;
    auto alloc = [&](size_t bytes) -> char* {
        char* r = p;
        p += (bytes + 255) & ~(size_t)255;
        return r;
    };
    unsigned short* xb    = (unsigned short*)alloc((size_t)NN * NN * 2);   // 134 MB
    unsigned short* wbT1  = (unsigned short*)alloc((size_t)NP * NN * 2);   // 10.5 MB
    unsigned short* wbT2  = (unsigned short*)alloc((size_t)NP * HPAD * 2);
    unsigned short* QT    = (unsigned short*)alloc((size_t)HPAD * HPAD * 2);
    float* ypart = (float*)alloc((size_t)2 * NN * NP * 4);                 // 42 MB
    float* y_self = (float*)alloc((size_t)NN * 200 * 4);                   // 6.6 MB
    unsigned short* y_simb = (unsigned short*)alloc((size_t)NN * 200 * 2); // 3.28 MB
    unsigned short* y_ratb = (unsigned short*)alloc((size_t)NN * 200 * 2); // 3.28 MB
    float* h1  = (float*)alloc((size_t)NN * 200 * 4);
    float* h2  = (float*)alloc((size_t)NN * 200 * 4);
    unsigned short* h1b = (unsigned short*)alloc((size_t)NN * HPAD * 2);
    unsigned short* h2b = (unsigned short*)alloc((size_t)NN * HPAD * 2);
    unsigned short* hQb = (unsigned short*)alloc((size_t)NN * HPAD * 2);
    int* deg_sim = (int*)alloc(NN * 4);
    int* deg_rat = (int*)alloc(NN * 4);
    int* off_sim = (int*)alloc((NN + 1) * 4);
    int* off_rat = (int*)alloc((NN + 1) * 4);
    int* pos_sim = (int*)alloc(NN * 4);
    int* pos_rat = (int*)alloc(NN * 4);
    int2* se_sim = (int2*)alloc((size_t)EE * 8);
    int2* se_rat = (int2*)alloc((size_t)EE * 8);
    float* hQ = ypart + (size_t)NN * NP;   // reuse plane 1 (free at decoder time)

    const dim3 blk(256);
    const dim3 tblk(32, 8);

    // conversions
    cvt_f2b_kernel<<<(NN * NN / 4) / 256, blk, 0, stream>>>(x, xb, NN * NN / 4);
    transpose_w_kernel<<<dim3(NN / 32, NP / 32), tblk, 0, stream>>>(
        w1_self, w1_sim, w1_rat, wbT1, NN, NN, 600);
    transpose_w_kernel<<<dim3(HPAD / 32, NP / 32), tblk, 0, stream>>>(
        w2_self, w2_sim, w2_rat, wbT2, HPAD, 200, 600);
    transpose_w_kernel<<<dim3(HPAD / 32, HPAD / 32), tblk, 0, stream>>>(
        Q, Q, Q, QT, HPAD, 200, 200);

    // edge sorts (dst-grouped, payload (src,eid))
    hipMemsetAsync(deg_sim, 0, 2 * NN * 4, stream);   // deg_sim+deg_rat contiguous
    hist_kernel<<<EE / 256, blk, 0, stream>>>(e_sim, deg_sim);
    hist_kernel<<<EE / 256, blk, 0, stream>>>(e_rat, deg_rat);
    scan_kernel<<<1, blk, 0, stream>>>(deg_sim, off_sim, pos_sim);
    scan_kernel<<<1, blk, 0, stream>>>(deg_rat, off_rat, pos_rat);
    reorder_kernel<<<EE / 256, blk, 0, stream>>>(e_sim, pos_sim, se_sim);
    reorder_kernel<<<EE / 256, blk, 0, stream>>>(e_rat, pos_rat, se_rat);

    // layer 1 (split-K = 2)
    gemm_mfma<<<dim3(NP / 128, NN / 128, 2), blk, 0, stream>>>(
        xb, wbT1, ypart, NN, NN / 2, NP, (size_t)NN * NP);
    combine_kernel<<<NN * 50 / 256, blk, 0, stream>>>(
        ypart, ypart + (size_t)NN * NP, y_self, y_simb, y_ratb);
    agg_pass_kernel<<<NN, blk, 0, stream>>>(y_simb, off_sim, se_sim,
                                            y_self, b1, h1, 0);
    agg_pass_kernel<<<NN, blk, 0, stream>>>(y_ratb, off_rat, se_rat,
                                            nullptr, nullptr, h1, 1);
    cvt_h_kernel<<<NN * 64 / 256, blk, 0, stream>>>(h1, h1b);

    // layer 2
    gemm_mfma<<<dim3(NP / 128, NN / 128, 1), blk, 0, stream>>>(
        h1b, wbT2, ypart, HPAD, HPAD, NP, 0);
    combine_kernel<<<NN * 50 / 256, blk, 0, stream>>>(
        ypart, nullptr, y_self, y_simb, y_ratb);
    agg_pass_kernel<<<NN, blk, 0, stream>>>(y_simb, off_sim, se_sim,
                                            y_self, b2, h2, 0);
    agg_pass_kernel<<<NN, blk, 0, stream>>>(y_ratb, off_rat, se_rat,
                                            nullptr, nullptr, h2, 0);
    cvt_h_kernel<<<NN * 64 / 256, blk, 0, stream>>>(h2, h2b);

    // decoder
    gemm_mfma<<<dim3(HPAD / 128, NN / 128, 1), blk, 0, stream>>>(
        h2b, QT, hQ, HPAD, HPAD, HPAD, 0);
    cvt_f2b_kernel<<<(NN * HPAD / 4) / 256, blk, 0, stream>>>(hQ, hQb, NN * HPAD / 4);
    pred_kernel<<<NN, blk, 0, stream>>>(hQb, h2b, off_rat, se_rat, mask, out);
}

// Round 5
// 978.372 us; speedup vs baseline: 1.0419x; 1.0419x over previous
//
#include <hip/hip_runtime.h>

#define NN 8192
#define EE 524288
#define HPAD 256   // hidden 200 padded to 256
#define NP 640     // 3*200 output cols padded to 640 (5 x 128 tiles)

using s16x8 = __attribute__((ext_vector_type(8))) short;
using f32x4 = __attribute__((ext_vector_type(4))) float;

__device__ __forceinline__ unsigned short f2b(float f) {
    unsigned u = __float_as_uint(f);
    u = (u + 0x7FFFu + ((u >> 16) & 1u)) >> 16;   // round-to-nearest-even
    return (unsigned short)u;
}
__device__ __forceinline__ float b2f(unsigned short u) {
    return __uint_as_float((unsigned)u << 16);
}

// async 16B global->LDS (direct DMA). Dest is wave-uniform base + lane*16.
__device__ __forceinline__ void async16(const unsigned short* g, unsigned short* l)
{
    __builtin_amdgcn_global_load_lds(
        (const __attribute__((address_space(1))) unsigned int*)g,
        (__attribute__((address_space(3))) unsigned int*)l, 16, 0, 0);
}

// ---------------- conversions ----------------

__global__ void cvt_f2b_kernel(const float* __restrict__ in,
                               unsigned short* __restrict__ out, int n4)
{
    int i = blockIdx.x * 256 + threadIdx.x;
    if (i >= n4) return;
    float4 v = ((const float4*)in)[i];
    ushort4 o;
    o.x = f2b(v.x); o.y = f2b(v.y); o.z = f2b(v.z); o.w = f2b(v.w);
    ((ushort4*)out)[i] = o;
}

// out[n][k] (bf16, [Nout, Kout]) = concat(w0|w1|w2)[k][n], zero-padded.
__global__ void transpose_w_kernel(const float* __restrict__ w0,
                                   const float* __restrict__ w1,
                                   const float* __restrict__ w2,
                                   unsigned short* __restrict__ out,
                                   int Kout, int Kreal, int Nreal)
{
    __shared__ float tile[32][33];
    const int kb = blockIdx.x << 5;
    const int nb = blockIdx.y << 5;
    const int tx = threadIdx.x, ty = threadIdx.y;   // 32 x 8
    const int n = nb + tx;
    const float* w = (n < 200) ? w0 : (n < 400) ? w1 : w2;
    const int c = (n < 200) ? n : (n < 400) ? n - 200 : n - 400;
#pragma unroll
    for (int i = 0; i < 4; ++i) {
        const int k = kb + ty + (i << 3);
        float v = 0.f;
        if (n < Nreal && k < Kreal) v = w[(size_t)k * 200 + c];
        tile[ty + (i << 3)][tx] = v;
    }
    __syncthreads();
#pragma unroll
    for (int i = 0; i < 4; ++i) {
        const int nn = nb + ty + (i << 3);
        out[(size_t)nn * Kout + kb + tx] = f2b(tile[tx][ty + (i << 3)]);
    }
}

// ---------------- MFMA GEMM: dbuf LDS + async DMA, 1 barrier per K-step ------
// C_plane[z][8192, ldc] = A[:, z*KC:(z+1)*KC] @ BT[:, z*KC:(z+1)*KC]^T
// LDS layout: slot s of row r holds k-chunk s^(r&7)  (conflict-free ds_read).
// Staging: lane l=(r=l>>3, c=l&7) DMAs global chunk c^r of row (w*8+r), landing
// at wave-uniform-base + l*16 = slot c of row r  => invariant holds.
// Pipeline: iter t issues DMA of tile t+1 into buf[t+1&1], computes buf[t&1],
// then __syncthreads (compiler's vmcnt(0)+barrier) — DMA in flight across the
// whole compute phase. Buf t+1&1's previous readers finished at end of t-1.
__global__ __launch_bounds__(256) void gemm_mfma(
    const unsigned short* __restrict__ A,
    const unsigned short* __restrict__ BT,
    float* __restrict__ C, unsigned short* __restrict__ Cb,
    int lda, int KC, int ldc, size_t planeStride)
{
    __shared__ unsigned short As[2][128 * 64];
    __shared__ unsigned short Bs[2][128 * 64];
    const int tid  = threadIdx.x;
    const int lane = tid & 63;
    const int w    = tid >> 6;
    const int row0 = blockIdx.y << 7;
    const int col0 = blockIdx.x << 7;
    const int z    = blockIdx.z;
    const int wm = (w >> 1) << 6;
    const int wn = (w & 1) << 6;

    const int sr = lane >> 3;             // row within wave's 8-row strip
    const int sc = (lane & 7) ^ sr;       // global chunk to fetch (xor-permuted)
    const size_t kbase = (size_t)z * KC + ((size_t)sc << 3);
    const unsigned short* aG = A  + (size_t)(row0 + w * 8 + sr) * lda + kbase;
    const unsigned short* bG = BT + (size_t)(col0 + w * 8 + sr) * lda + kbase;
    const int ldsOff = w * 8;             // wave's strip base row

    const f32x4 zero = {0.f, 0.f, 0.f, 0.f};
    f32x4 acc[4][4];
#pragma unroll
    for (int i = 0; i < 4; ++i)
#pragma unroll
        for (int j = 0; j < 4; ++j) acc[i][j] = zero;

    // stage tile 0 into buf 0
#pragma unroll
    for (int it = 0; it < 4; ++it) {
        async16(aG + (size_t)(it * 32) * lda, &As[0][(it * 32 + ldsOff) << 6]);
        async16(bG + (size_t)(it * 32) * lda, &Bs[0][(it * 32 + ldsOff) << 6]);
    }
    __syncthreads();

    const int T = KC >> 6;
    for (int t = 0; t < T; ++t) {
        const int cur = t & 1;
        if (t + 1 < T) {
            const int ko = (t + 1) << 6;
#pragma unroll
            for (int it = 0; it < 4; ++it) {
                async16(aG + (size_t)(it * 32) * lda + ko,
                        &As[cur ^ 1][(it * 32 + ldsOff) << 6]);
                async16(bG + (size_t)(it * 32) * lda + ko,
                        &Bs[cur ^ 1][(it * 32 + ldsOff) << 6]);
            }
        }
#pragma unroll
        for (int kk = 0; kk < 2; ++kk) {
            const int q  = (kk << 2) + (lane >> 4);
            const int sl = (q ^ (lane & 7)) << 3;
            s16x8 af[4], bfv[4];
#pragma unroll
            for (int i = 0; i < 4; ++i) {
                const int rm = wm + (i << 4) + (lane & 15);
                af[i]  = *(const s16x8*)(&As[cur][(rm << 6) + sl]);
                const int rn = wn + (i << 4) + (lane & 15);
                bfv[i] = *(const s16x8*)(&Bs[cur][(rn << 6) + sl]);
            }
#pragma unroll
            for (int i = 0; i < 4; ++i)
#pragma unroll
                for (int j = 0; j < 4; ++j)
                    acc[i][j] = __builtin_amdgcn_mfma_f32_16x16x32_bf16(
                        af[i], bfv[j], acc[i][j], 0, 0, 0);
        }
        __syncthreads();   // drains this iter's DMA; protects buf swap
    }

    const int cr = (lane >> 4) << 2;      // C/D: row = quad*4 + r, col = lane&15
    const int cc = lane & 15;
    if (Cb) {
#pragma unroll
        for (int i = 0; i < 4; ++i)
#pragma unroll
            for (int j = 0; j < 4; ++j)
#pragma unroll
                for (int r = 0; r < 4; ++r)
                    Cb[(size_t)(row0 + wm + (i << 4) + cr + r) * ldc
                       + (col0 + wn + (j << 4) + cc)] = f2b(acc[i][j][r]);
    } else {
        float* Cp = C + (size_t)z * planeStride;
#pragma unroll
        for (int i = 0; i < 4; ++i)
#pragma unroll
            for (int j = 0; j < 4; ++j)
#pragma unroll
                for (int r = 0; r < 4; ++r)
                    Cp[(size_t)(row0 + wm + (i << 4) + cr + r) * ldc
                       + (col0 + wn + (j << 4) + cc)] = acc[i][j][r];
    }
}

// ---------------- combine: fp32 self + two contiguous bf16 message arrays ----
// y_simb / y_ratb: [8192,200] bf16 (3.28 MB each -> fits per-XCD 4MB L2)
__global__ void combine_kernel(const float* __restrict__ p0,
                               const float* __restrict__ p1,
                               float* __restrict__ y_self,
                               unsigned short* __restrict__ y_simb,
                               unsigned short* __restrict__ y_ratb)
{
    int t = blockIdx.x * 256 + threadIdx.x;    // n*50 + j4chunk
    int n = t / 50, j4 = (t - n * 50) << 2;
    const float* a = p0 + (size_t)n * NP;
    float4 s = *(const float4*)(a + j4);
    float4 m = *(const float4*)(a + 200 + j4);
    float4 r = *(const float4*)(a + 400 + j4);
    if (p1) {
        const float* b = p1 + (size_t)n * NP;
        float4 s2 = *(const float4*)(b + j4);
        float4 m2 = *(const float4*)(b + 200 + j4);
        float4 r2 = *(const float4*)(b + 400 + j4);
        s.x += s2.x; s.y += s2.y; s.z += s2.z; s.w += s2.w;
        m.x += m2.x; m.y += m2.y; m.z += m2.z; m.w += m2.w;
        r.x += r2.x; r.y += r2.y; r.z += r2.z; r.w += r2.w;
    }
    *(float4*)(y_self + (size_t)n * 200 + j4) = s;
    ushort4 mo, ro;
    mo.x = f2b(m.x); mo.y = f2b(m.y); mo.z = f2b(m.z); mo.w = f2b(m.w);
    ro.x = f2b(r.x); ro.y = f2b(r.y); ro.z = f2b(r.z); ro.w = f2b(r.w);
    *(ushort4*)(y_simb + (size_t)n * 200 + j4) = mo;
    *(ushort4*)(y_ratb + (size_t)n * 200 + j4) = ro;
}

// ---------------- edge sort (counting sort by dst, payload = (src, eid)) -----

__global__ void hist_kernel(const int* __restrict__ edges, int* __restrict__ deg)
{
    int e = blockIdx.x * 256 + threadIdx.x;
    if (e < EE) atomicAdd(&deg[edges[EE + e]], 1);
}

__global__ void scan_kernel(const int* __restrict__ deg,
                            int* __restrict__ off, int* __restrict__ pos)
{
    __shared__ int part[256];
    const int t = threadIdx.x;
    const int base = t * 32;
    int s = 0;
#pragma unroll
    for (int i = 0; i < 32; ++i) s += deg[base + i];
    part[t] = s;
    __syncthreads();
    for (int d = 1; d < 256; d <<= 1) {
        int v = (t >= d) ? part[t - d] : 0;
        __syncthreads();
        part[t] += v;
        __syncthreads();
    }
    int run = (t == 0) ? 0 : part[t - 1];
    for (int i = 0; i < 32; ++i) {
        off[base + i] = run;
        pos[base + i] = run;
        run += deg[base + i];
    }
    if (t == 255) off[NN] = run;
}

__global__ void reorder_kernel(const int* __restrict__ edges,
                               int* __restrict__ pos, int2* __restrict__ se)
{
    int e = blockIdx.x * 256 + threadIdx.x;
    if (e >= EE) return;
    int p = atomicAdd(&pos[edges[EE + e]], 1);
    se[p] = make_int2(edges[e], e);
}

// ---------------- aggregation pass (one message type per launch) ----------
// pass A (y_self != null): h = y_self + bias + sum_msg        (writes h fp32)
// pass B (hb != null):     hb = bf16(relu?(h + sum_msg)), padded to HPAD
__global__ __launch_bounds__(256) void agg_pass_kernel(
    const unsigned short* __restrict__ msg,   // [8192,200] bf16, L2-resident
    const int* __restrict__ off, const int2* __restrict__ se,
    const float* __restrict__ y_self, const float* __restrict__ bias,
    float* __restrict__ h, unsigned short* __restrict__ hb, int relu)
{
    __shared__ float part[4][200];
    const int n = blockIdx.x;
    const int w = threadIdx.x >> 6;
    const int lane = threadIdx.x & 63;
    const int j4 = lane << 2;
    const bool act = lane < 50;

    float4 acc = {0.f, 0.f, 0.f, 0.f};
    const int e1 = off[n + 1];
    for (int i = off[n] + w; i < e1; i += 4) {
        const int src = se[i].x;
        if (act) {
            ushort4 v = *(const ushort4*)(msg + (size_t)src * 200 + j4);
            acc.x += b2f(v.x); acc.y += b2f(v.y);
            acc.z += b2f(v.z); acc.w += b2f(v.w);
        }
    }
    if (act) *(float4*)&part[w][j4] = acc;
    __syncthreads();
    const int j = threadIdx.x;
    if (j < 200) {
        float v = part[0][j] + part[1][j] + part[2][j] + part[3][j];
        if (y_self) v += y_self[(size_t)n * 200 + j] + bias[j];
        else        v += h[(size_t)n * 200 + j];
        if (relu) v = fmaxf(v, 0.f);
        if (hb) hb[((size_t)n << 8) + j] = f2b(v);
        else    h[(size_t)n * 200 + j] = v;
    } else if (hb && j < HPAD) {
        hb[((size_t)n << 8) + j] = 0;     // zero the pad (ws is poisoned)
    }
}

// ---------------- decoder: dst-grouped, hQ gathered from L2-resident array ---
__global__ __launch_bounds__(256) void pred_kernel(
    const unsigned short* __restrict__ hQb,  // [8192, HPAD] bf16
    const unsigned short* __restrict__ h2b,  // [8192, HPAD] bf16
    const int* __restrict__ off, const int2* __restrict__ se,
    const int* __restrict__ mask, float* __restrict__ out)
{
    const int n = blockIdx.x;
    const int w = threadIdx.x >> 6;
    const int lane = threadIdx.x & 63;
    float4 b = {0.f, 0.f, 0.f, 0.f};
    if (lane < 50) {
        ushort4 v = *(const ushort4*)(h2b + ((size_t)n << 8) + (lane << 2));
        b.x = b2f(v.x); b.y = b2f(v.y); b.z = b2f(v.z); b.w = b2f(v.w);
    }
    const int e1 = off[n + 1];
    for (int i = off[n] + w; i < e1; i += 4) {
        const int2 p = ((const int2*)se)[i];
        float s = 0.f;
        if (lane < 50) {
            ushort4 a = *(const ushort4*)(hQb + ((size_t)p.x << 8) + (lane << 2));
            s = fmaf(b2f(a.x), b.x, fmaf(b2f(a.y), b.y,
                fmaf(b2f(a.z), b.z, b2f(a.w) * b.w)));
        }
#pragma unroll
        for (int o = 32; o > 0; o >>= 1) s += __shfl_down(s, o, 64);
        if (lane == 0) out[p.y] = mask[p.y] ? (s + 3.5f) : 0.f;
    }
}

// ---------------- launch ----------------
extern "C" void kernel_launch(void* const* d_in, const int* in_sizes, int n_in,
                              void* d_out, int out_size, void* d_ws, size_t ws_size,
                              hipStream_t stream)
{
    const float* x       = (const float*)d_in[0];
    const int*   e_sim   = (const int*)d_in[1];
    const int*   e_rat   = (const int*)d_in[2];
    const int*   mask    = (const int*)d_in[3];
    const float* w1_self = (const float*)d_in[4];
    const float* w1_sim  = (const float*)d_in[5];
    const float* w1_rat  = (const float*)d_in[6];
    const float* b1      = (const float*)d_in[7];
    const float* w2_self = (const float*)d_in[8];
    const float* w2_sim  = (const float*)d_in[9];
    const float* w2_rat  = (const float*)d_in[10];
    const float* b2      = (const float*)d_in[11];
    const float* Q       = (const float*)d_in[12];
    float* out = (float*)d_out;

    char* p = (char*)d_ws;
    auto alloc = [&](size_t bytes) -> char* {
        char* r = p;
        p += (bytes + 255) & ~(size_t)255;
        return r;
    };
    unsigned short* xb    = (unsigned short*)alloc((size_t)NN * NN * 2);   // 134 MB
    unsigned short* wbT1  = (unsigned short*)alloc((size_t)NP * NN * 2);   // 10.5 MB
    unsigned short* wbT2  = (unsigned short*)alloc((size_t)NP * HPAD * 2);
    unsigned short* QT    = (unsigned short*)alloc((size_t)HPAD * HPAD * 2);
    float* ypart = (float*)alloc((size_t)2 * NN * NP * 4);                 // 42 MB
    float* y_self = (float*)alloc((size_t)NN * 200 * 4);                   // 6.6 MB
    unsigned short* y_simb = (unsigned short*)alloc((size_t)NN * 200 * 2); // 3.28 MB
    unsigned short* y_ratb = (unsigned short*)alloc((size_t)NN * 200 * 2); // 3.28 MB
    float* h1  = (float*)alloc((size_t)NN * 200 * 4);
    float* h2  = (float*)alloc((size_t)NN * 200 * 4);
    unsigned short* h1b = (unsigned short*)alloc((size_t)NN * HPAD * 2);
    unsigned short* h2b = (unsigned short*)alloc((size_t)NN * HPAD * 2);
    unsigned short* hQb = (unsigned short*)alloc((size_t)NN * HPAD * 2);
    int* deg_sim = (int*)alloc(NN * 4);
    int* deg_rat = (int*)alloc(NN * 4);
    int* off_sim = (int*)alloc((NN + 1) * 4);
    int* off_rat = (int*)alloc((NN + 1) * 4);
    int* pos_sim = (int*)alloc(NN * 4);
    int* pos_rat = (int*)alloc(NN * 4);
    int2* se_sim = (int2*)alloc((size_t)EE * 8);
    int2* se_rat = (int2*)alloc((size_t)EE * 8);

    const dim3 blk(256);
    const dim3 tblk(32, 8);

    // conversions
    cvt_f2b_kernel<<<(NN * NN / 4) / 256, blk, 0, stream>>>(x, xb, NN * NN / 4);
    transpose_w_kernel<<<dim3(NN / 32, NP / 32), tblk, 0, stream>>>(
        w1_self, w1_sim, w1_rat, wbT1, NN, NN, 600);
    transpose_w_kernel<<<dim3(HPAD / 32, NP / 32), tblk, 0, stream>>>(
        w2_self, w2_sim, w2_rat, wbT2, HPAD, 200, 600);
    transpose_w_kernel<<<dim3(HPAD / 32, HPAD / 32), tblk, 0, stream>>>(
        Q, Q, Q, QT, HPAD, 200, 200);

    // edge sorts (dst-grouped, payload (src,eid))
    hipMemsetAsync(deg_sim, 0, 2 * NN * 4, stream);   // deg_sim+deg_rat contiguous
    hist_kernel<<<EE / 256, blk, 0, stream>>>(e_sim, deg_sim);
    hist_kernel<<<EE / 256, blk, 0, stream>>>(e_rat, deg_rat);
    scan_kernel<<<1, blk, 0, stream>>>(deg_sim, off_sim, pos_sim);
    scan_kernel<<<1, blk, 0, stream>>>(deg_rat, off_rat, pos_rat);
    reorder_kernel<<<EE / 256, blk, 0, stream>>>(e_sim, pos_sim, se_sim);
    reorder_kernel<<<EE / 256, blk, 0, stream>>>(e_rat, pos_rat, se_rat);

    // layer 1 (split-K = 2)
    gemm_mfma<<<dim3(NP / 128, NN / 128, 2), blk, 0, stream>>>(
        xb, wbT1, ypart, nullptr, NN, NN / 2, NP, (size_t)NN * NP);
    combine_kernel<<<NN * 50 / 256, blk, 0, stream>>>(
        ypart, ypart + (size_t)NN * NP, y_self, y_simb, y_ratb);
    agg_pass_kernel<<<NN, blk, 0, stream>>>(y_simb, off_sim, se_sim,
                                            y_self, b1, h1, nullptr, 0);
    agg_pass_kernel<<<NN, blk, 0, stream>>>(y_ratb, off_rat, se_rat,
                                            nullptr, nullptr, h1, h1b, 1);

    // layer 2
    gemm_mfma<<<dim3(NP / 128, NN / 128, 1), blk, 0, stream>>>(
        h1b, wbT2, ypart, nullptr, HPAD, HPAD, NP, 0);
    combine_kernel<<<NN * 50 / 256, blk, 0, stream>>>(
        ypart, nullptr, y_self, y_simb, y_ratb);
    agg_pass_kernel<<<NN, blk, 0, stream>>>(y_simb, off_sim, se_sim,
                                            y_self, b2, h2, nullptr, 0);
    agg_pass_kernel<<<NN, blk, 0, stream>>>(y_ratb, off_rat, se_rat,
                                            nullptr, nullptr, h2, h2b, 0);

    // decoder (GEMM emits bf16 directly into hQb)
    gemm_mfma<<<dim3(HPAD / 128, NN / 128, 1), blk, 0, stream>>>(
        h2b, QT, nullptr, hQb, HPAD, HPAD, HPAD, 0);
    pred_kernel<<<NN, blk, 0, stream>>>(hQb, h2b, off_rat, se_rat, mask, out);
}